// Round 2
// baseline (2635.376 us; speedup 1.0000x reference)
//
#include <hip/hip_runtime.h>
#include <hip/hip_cooperative_groups.h>
#include <math.h>

namespace cg = cooperative_groups;

#define HD   512
#define H3   1536
#define SLEN 48
#define TLEN 48
#define BSZ  32
#define VOUT 32000

__device__ __forceinline__ float sigm(float x) { return 1.0f / (1.0f + __expf(-x)); }

typedef __attribute__((ext_vector_type(8))) __bf16 bf16x8;
typedef __attribute__((ext_vector_type(4))) float f32x4;

// ---------------------------------------------------------------------------
// split fp32 -> bf16 hi/lo arrays (8 elems/thread)
// ---------------------------------------------------------------------------
__global__ __launch_bounds__(256) void split_w(const float* __restrict__ src,
                                               __bf16* __restrict__ hi,
                                               __bf16* __restrict__ lo, int n8)
{
    int i = blockIdx.x * 256 + threadIdx.x;
    if (i >= n8) return;
    float4 a = ((const float4*)src)[i * 2];
    float4 b = ((const float4*)src)[i * 2 + 1];
    float v[8] = {a.x, a.y, a.z, a.w, b.x, b.y, b.z, b.w};
    bf16x8 h, l;
#pragma unroll
    for (int j = 0; j < 8; j++) {
        __bf16 hb = (__bf16)v[j];
        h[j] = hb;
        l[j] = (__bf16)(v[j] - (float)hb);
    }
    ((bf16x8*)hi)[i] = h;
    ((bf16x8*)lo)[i] = l;
}

// ---------------------------------------------------------------------------
// MFMA bf16x3-split NT GEMM, fp32 inputs (in-kernel split), optional gather
// and optional split-bf16 output. 128x128 block, 4 waves (2x2), 64x64/wave.
// ---------------------------------------------------------------------------
template <int GATHER, int ACT, int OSPLIT>
__global__ __launch_bounds__(256, 2) void gemm_mfma(
    const float* __restrict__ A, const float* __restrict__ emb,
    const int* __restrict__ tokens, const float* __restrict__ Bt,
    const float* __restrict__ bias, float* __restrict__ Cout,
    __bf16* __restrict__ Chi, __bf16* __restrict__ Clo,
    int M, int N, int K)
{
    const int lane = threadIdx.x & 63;
    const int wave = threadIdx.x >> 6;        // 0..3
    const int wm = wave & 1, wn = wave >> 1;  // 2x2 waves of 64x64
    const int m0 = blockIdx.x * 128 + wm * 64;
    const int n0 = blockIdx.y * 128 + wn * 64;
    const int rl = lane & 15;
    const int kg = lane >> 4;

    const float* arow[4];
    const float* wrow[4];
#pragma unroll
    for (int f = 0; f < 4; f++) {
        int row = m0 + f * 16 + rl;
        if (GATHER == 0) {
            arow[f] = A + (size_t)row * K + kg * 8;
        } else if (GATHER == 1) {
            arow[f] = emb + (size_t)tokens[row] * K + kg * 8;
        } else {
            int t = row >> 5, b = row & 31;
            int tok = (t == 0) ? 1 : tokens[(t - 1) * 32 + b];
            arow[f] = emb + (size_t)tok * K + kg * 8;
        }
        wrow[f] = Bt + (size_t)(n0 + f * 16 + rl) * K + kg * 8;
    }

    f32x4 acc[4][4] = {};

    for (int k0 = 0; k0 < K; k0 += 32) {
        bf16x8 ah[4], al[4], wh[4], wl[4];
#pragma unroll
        for (int f = 0; f < 4; f++) {
            float4 x0 = *(const float4*)(arow[f] + k0);
            float4 x1 = *(const float4*)(arow[f] + k0 + 4);
            float4 y0 = *(const float4*)(wrow[f] + k0);
            float4 y1 = *(const float4*)(wrow[f] + k0 + 4);
            float xs[8] = {x0.x, x0.y, x0.z, x0.w, x1.x, x1.y, x1.z, x1.w};
            float ys[8] = {y0.x, y0.y, y0.z, y0.w, y1.x, y1.y, y1.z, y1.w};
            bf16x8 xh, xl, yh, yl;
#pragma unroll
            for (int j = 0; j < 8; j++) {
                __bf16 hb = (__bf16)xs[j];
                xh[j] = hb;
                xl[j] = (__bf16)(xs[j] - (float)hb);
                __bf16 hc = (__bf16)ys[j];
                yh[j] = hc;
                yl[j] = (__bf16)(ys[j] - (float)hc);
            }
            ah[f] = xh; al[f] = xl; wh[f] = yh; wl[f] = yl;
        }
#pragma unroll
        for (int fm = 0; fm < 4; fm++)
#pragma unroll
            for (int fn = 0; fn < 4; fn++) {
                acc[fm][fn] = __builtin_amdgcn_mfma_f32_16x16x32_bf16(
                    ah[fm], wh[fn], acc[fm][fn], 0, 0, 0);
                acc[fm][fn] = __builtin_amdgcn_mfma_f32_16x16x32_bf16(
                    ah[fm], wl[fn], acc[fm][fn], 0, 0, 0);
                acc[fm][fn] = __builtin_amdgcn_mfma_f32_16x16x32_bf16(
                    al[fm], wh[fn], acc[fm][fn], 0, 0, 0);
            }
    }

    // C/D layout: col = lane&15, row = (lane>>4)*4 + reg
#pragma unroll
    for (int fn = 0; fn < 4; fn++) {
        float bb = bias[n0 + fn * 16 + rl];
#pragma unroll
        for (int fm = 0; fm < 4; fm++) {
            int mrow = m0 + fm * 16 + kg * 4;
            int ncol = n0 + fn * 16 + rl;
#pragma unroll
            for (int r = 0; r < 4; r++) {
                float v = acc[fm][fn][r] + bb;
                if (ACT == 1) v = tanhf(v);
                if (OSPLIT) {
                    __bf16 hh = (__bf16)v;
                    Chi[(size_t)(mrow + r) * N + ncol] = hh;
                    Clo[(size_t)(mrow + r) * N + ncol] = (__bf16)(v - (float)hh);
                } else {
                    Cout[(size_t)(mrow + r) * N + ncol] = v;
                }
            }
        }
    }
}

// ---------------------------------------------------------------------------
// Logits GEMM: A pre-split bf16 hi/lo [M,K]; W fp32 [N,K] staged+split via LDS
// once per (block, element). Block covers 256 m x 128 n; 4 waves of 64m each.
// ---------------------------------------------------------------------------
__global__ __launch_bounds__(256, 1) void gemm_logits(
    const __bf16* __restrict__ Ahi, const __bf16* __restrict__ Alo,
    const float* __restrict__ W, const float* __restrict__ bias,
    float* __restrict__ Cout, int M, int N, int K)
{
    __shared__ __align__(16) __bf16 WL[2][8][64][8];   // 16 KB
    const int lane = threadIdx.x & 63;
    const int wave = threadIdx.x >> 6;
    const int m0 = blockIdx.x * 256 + wave * 64;
    const int n0 = blockIdx.y * 128;
    const int rl = lane & 15, kg = lane >> 4;

    const __bf16* ap[4];
    const __bf16* alp[4];
#pragma unroll
    for (int mt = 0; mt < 4; mt++) {
        ap[mt]  = Ahi + (size_t)(m0 + mt * 16 + rl) * K + kg * 8;
        alp[mt] = Alo + (size_t)(m0 + mt * 16 + rl) * K + kg * 8;
    }

    const int snt = threadIdx.x >> 5;         // 0..7 (staging n-tile)
    const int sl0 = (threadIdx.x & 31) * 2;   // staging lane pair

    f32x4 acc[4][8] = {};

    for (int kt = 0; kt < K; kt += 32) {
#pragma unroll
        for (int q = 0; q < 2; q++) {
            int l = sl0 + q;
            const float* wr = W + (size_t)(n0 + snt * 16 + (l & 15)) * K + kt + (l >> 4) * 8;
            float4 x0 = *(const float4*)wr;
            float4 x1 = *(const float4*)(wr + 4);
            float v[8] = {x0.x, x0.y, x0.z, x0.w, x1.x, x1.y, x1.z, x1.w};
            bf16x8 h, lo_;
#pragma unroll
            for (int j = 0; j < 8; j++) {
                __bf16 hb = (__bf16)v[j];
                h[j] = hb;
                lo_[j] = (__bf16)(v[j] - (float)hb);
            }
            *(bf16x8*)&WL[0][snt][l][0] = h;
            *(bf16x8*)&WL[1][snt][l][0] = lo_;
        }
        __syncthreads();
        bf16x8 a_h[4], a_l[4];
#pragma unroll
        for (int mt = 0; mt < 4; mt++) {
            a_h[mt] = *(const bf16x8*)(ap[mt] + kt);
            a_l[mt] = *(const bf16x8*)(alp[mt] + kt);
        }
#pragma unroll
        for (int nt = 0; nt < 8; nt++) {
            bf16x8 wh = *(const bf16x8*)&WL[0][nt][lane][0];
            bf16x8 wl = *(const bf16x8*)&WL[1][nt][lane][0];
#pragma unroll
            for (int mt = 0; mt < 4; mt++) {
                acc[mt][nt] = __builtin_amdgcn_mfma_f32_16x16x32_bf16(
                    a_h[mt], wh, acc[mt][nt], 0, 0, 0);
                acc[mt][nt] = __builtin_amdgcn_mfma_f32_16x16x32_bf16(
                    a_h[mt], wl, acc[mt][nt], 0, 0, 0);
                acc[mt][nt] = __builtin_amdgcn_mfma_f32_16x16x32_bf16(
                    a_l[mt], wh, acc[mt][nt], 0, 0, 0);
            }
        }
        __syncthreads();
    }

#pragma unroll
    for (int nt = 0; nt < 8; nt++) {
        int col = n0 + nt * 16 + rl;
        float bb = bias[col];
#pragma unroll
        for (int mt = 0; mt < 4; mt++) {
            int row = m0 + mt * 16 + kg * 4;
#pragma unroll
            for (int r = 0; r < 4; r++)
                Cout[(size_t)(row + r) * N + col] = acc[mt][nt][r] + bb;
        }
    }
}

// ---------------------------------------------------------------------------
// Persistent cooperative recurrence. 64 wgs x 128 thr (2 waves).
// wg w: dir = w>>5 (0 fwd/dec, 1 bwd), hidden chunk i0 = (w&31)*16.
// LDS holds this wg's Whh slice (3 gates x 16 rows, K=512) as bf16 hi/lo
// pre-arranged in MFMA B-fragment order. Wave = m-tile (16 batches).
// h stored fp32 (outputs) + double-buffered bf16 hi/lo (next-step A operand).
// ---------------------------------------------------------------------------
typedef __bf16 wlds_t[3][16][64][8];

__device__ __forceinline__ void load_w(wlds_t* Wlds, const __bf16* __restrict__ Whi,
                                       const __bf16* __restrict__ Wlo, int i0, int tid)
{
    for (int idx = tid; idx < 3 * 16 * 64; idx += 128) {
        int g = idx >> 10, rem = idx & 1023, kk = rem >> 6, l = rem & 63;
        size_t src = (size_t)(g * HD + i0 + (l & 15)) * HD + kk * 32 + (l >> 4) * 8;
        *(bf16x8*)&Wlds[0][g][kk][l][0] = *(const bf16x8*)&Whi[src];
        *(bf16x8*)&Wlds[1][g][kk][l][0] = *(const bf16x8*)&Wlo[src];
    }
    __syncthreads();
}

__device__ __forceinline__ void gru_step_mfma(
    const wlds_t* Wlds, int wave, int lane, int i0, int tfirst,
    const float* __restrict__ GIt, const __bf16* __restrict__ Hsp_prev,
    const float* __restrict__ bhh, const float* __restrict__ hprev,
    float* __restrict__ hout, __bf16* __restrict__ Hsp_out)
{
    f32x4 acc[3] = {};
    if (!tfirst) {
        const __bf16* ah = Hsp_prev + (size_t)(wave * 16 + (lane & 15)) * HD + (lane >> 4) * 8;
        const __bf16* al = ah + 32 * HD;
#pragma unroll
        for (int kk = 0; kk < 16; kk++) {
            bf16x8 Af = *(const bf16x8*)(ah + kk * 32);
            bf16x8 Al = *(const bf16x8*)(al + kk * 32);
#pragma unroll
            for (int g = 0; g < 3; g++) {
                bf16x8 Wh = *(const bf16x8*)&Wlds[0][g][kk][lane][0];
                bf16x8 Wl = *(const bf16x8*)&Wlds[1][g][kk][lane][0];
                acc[g] = __builtin_amdgcn_mfma_f32_16x16x32_bf16(Af, Wh, acc[g], 0, 0, 0);
                acc[g] = __builtin_amdgcn_mfma_f32_16x16x32_bf16(Af, Wl, acc[g], 0, 0, 0);
                acc[g] = __builtin_amdgcn_mfma_f32_16x16x32_bf16(Al, Wh, acc[g], 0, 0, 0);
            }
        }
    }
    const int ig = i0 + (lane & 15);
    const int bb = wave * 16 + (lane >> 4) * 4;
    float b_r = bhh[ig], b_z = bhh[HD + ig], b_n = bhh[2 * HD + ig];
#pragma unroll
    for (int r = 0; r < 4; r++) {
        int b = bb + r;
        float gr = acc[0][r] + GIt[(size_t)b * H3 + ig] + b_r;
        float gz = acc[1][r] + GIt[(size_t)b * H3 + HD + ig] + b_z;
        float gn = GIt[(size_t)b * H3 + 2 * HD + ig];
        float ghn = acc[2][r] + b_n;
        float rg = sigm(gr), zg = sigm(gz);
        float ng = tanhf(gn + rg * ghn);
        float hpi = tfirst ? 0.f : hprev[(size_t)b * HD + ig];
        float h = (1.f - zg) * ng + zg * hpi;
        hout[(size_t)b * HD + ig] = h;
        __bf16 hh = (__bf16)h;
        Hsp_out[(size_t)b * HD + ig] = hh;
        Hsp_out[32 * HD + (size_t)b * HD + ig] = (__bf16)(h - (float)hh);
    }
}

__global__ __launch_bounds__(128) void recurrence(
    const float* __restrict__ GIf, const float* __restrict__ GIb,
    const float* __restrict__ GId,
    const __bf16* __restrict__ Wfh, const __bf16* __restrict__ Wfl,
    const __bf16* __restrict__ Wbh, const __bf16* __restrict__ Wbl,
    const __bf16* __restrict__ Wdh, const __bf16* __restrict__ Wdl,
    const float* __restrict__ bhf, const float* __restrict__ bhb,
    const float* __restrict__ bhd,
    float* __restrict__ Hf, float* __restrict__ Hb, float* __restrict__ H2,
    __bf16* __restrict__ Hsp, float* __restrict__ ES)
{
    __shared__ __align__(16) __bf16 Wlds[2][3][16][64][8];   // 96 KB
    cg::grid_group grid = cg::this_grid();
    const int w = blockIdx.x;
    const int dir = w >> 5;
    const int i0 = (w & 31) * 16;
    const int wave = threadIdx.x >> 6, lane = threadIdx.x & 63;
    const int tid = threadIdx.x;
    // Hsp layout: [dir(2)][parity(2)] blocks of (hi[32][512], lo[32][512])
    const size_t HSPB = (size_t)2 * 32 * HD;   // elems per (dir,parity) block

    load_w(Wlds, dir ? Wbh : Wfh, dir ? Wbl : Wfl, i0, tid);

    // ---- phase 1: encoder (fwd on wgs 0-31, bwd on wgs 32-63) ----
    for (int t = 0; t < SLEN; t++) {
        if (dir == 0) {
            gru_step_mfma(Wlds, wave, lane, i0, t == 0,
                GIf + (size_t)t * BSZ * H3,
                Hsp + (size_t)(0 * 2 + ((t + 1) & 1)) * HSPB,
                bhf, t ? Hf + (size_t)(t - 1) * BSZ * HD : (const float*)0,
                Hf + (size_t)t * BSZ * HD,
                Hsp + (size_t)(0 * 2 + (t & 1)) * HSPB);
        } else {
            int tb = SLEN - 1 - t;
            gru_step_mfma(Wlds, wave, lane, i0, t == 0,
                GIb + (size_t)tb * BSZ * H3,
                Hsp + (size_t)(1 * 2 + ((t + 1) & 1)) * HSPB,
                bhb, t ? Hb + (size_t)(tb + 1) * BSZ * HD : (const float*)0,
                Hb + (size_t)tb * BSZ * HD,
                Hsp + (size_t)(1 * 2 + (t & 1)) * HSPB);
        }
        __threadfence();
        grid.sync();
    }

    // ---- interphase: wgs 0-31 reload decoder weights; wgs 32-63 do ES ----
    if (dir == 0) {
        load_w(Wlds, Wdh, Wdl, i0, tid);
    } else {
        int etid = (w - 32) * 128 + tid;      // 0..4095
        const float4* hf4 = (const float4*)Hf;
        const float4* hb4 = (const float4*)Hb;
        float4* es4 = (float4*)ES;
        for (int idx = etid; idx < SLEN * BSZ * HD / 4; idx += 4096) {
            float4 a = hf4[idx], b = hb4[idx];
            float4 r = {a.x + b.x, a.y + b.y, a.z + b.z, a.w + b.w};
            es4[idx] = r;
        }
    }

    // ---- phase 2: decoder on wgs 0-31 (h0 = Hf[47]; parity continues) ----
    for (int t = 0; t < TLEN; t++) {
        if (dir == 0) {
            gru_step_mfma(Wlds, wave, lane, i0, 0,
                GId + (size_t)t * BSZ * H3,
                Hsp + (size_t)(0 * 2 + ((t + 1) & 1)) * HSPB,
                bhd,
                t ? H2 + (size_t)(t - 1) * BSZ * HD
                  : Hf + (size_t)(SLEN - 1) * BSZ * HD,
                H2 + (size_t)t * BSZ * HD,
                Hsp + (size_t)(0 * 2 + (t & 1)) * HSPB);
        }
        __threadfence();
        grid.sync();
    }
}

// ---------------------------------------------------------------------------
// Attention: one wave per (t,b). scores over s -> softmax -> ctx.
// ---------------------------------------------------------------------------
__global__ __launch_bounds__(256) void attention(
    const float* __restrict__ H2, const float* __restrict__ ES,
    float* __restrict__ CTX)
{
    const int wid = (blockIdx.x * 256 + threadIdx.x) >> 6;   // 0..1535
    const int lane = threadIdx.x & 63;
    const int t = wid >> 5, b = wid & 31;

    const float4* q = (const float4*)(H2 + ((size_t)t * BSZ + b) * HD);
    float4 q1 = q[lane], q2 = q[lane + 64];

    float sc = -1e30f;
    for (int s = 0; s < SLEN; s++) {
        const float4* e = (const float4*)(ES + ((size_t)s * BSZ + b) * HD);
        float4 e1 = e[lane], e2 = e[lane + 64];
        float p = q1.x * e1.x + q1.y * e1.y + q1.z * e1.z + q1.w * e1.w +
                  q2.x * e2.x + q2.y * e2.y + q2.z * e2.z + q2.w * e2.w;
#pragma unroll
        for (int d = 32; d >= 1; d >>= 1) p += __shfl_xor(p, d, 64);
        if (lane == s) sc = p;
    }
    float mx = sc;
#pragma unroll
    for (int d = 32; d >= 1; d >>= 1) mx = fmaxf(mx, __shfl_xor(mx, d, 64));
    float ex = (lane < SLEN) ? __expf(sc - mx) : 0.f;
    float sum = ex;
#pragma unroll
    for (int d = 32; d >= 1; d >>= 1) sum += __shfl_xor(sum, d, 64);
    float a = ex / sum;

    float4 c1 = {0.f, 0.f, 0.f, 0.f}, c2 = {0.f, 0.f, 0.f, 0.f};
    for (int s = 0; s < SLEN; s++) {
        float as = __shfl(a, s, 64);
        const float4* e = (const float4*)(ES + ((size_t)s * BSZ + b) * HD);
        float4 e1 = e[lane], e2 = e[lane + 64];
        c1.x = fmaf(as, e1.x, c1.x); c1.y = fmaf(as, e1.y, c1.y);
        c1.z = fmaf(as, e1.z, c1.z); c1.w = fmaf(as, e1.w, c1.w);
        c2.x = fmaf(as, e2.x, c2.x); c2.y = fmaf(as, e2.y, c2.y);
        c2.z = fmaf(as, e2.z, c2.z); c2.w = fmaf(as, e2.w, c2.w);
    }
    float4* co = (float4*)(CTX + ((size_t)t * BSZ + b) * HD);
    co[lane] = c1;
    co[lane + 64] = c2;
}

// CC[r, 0:512] = H2[r], CC[r, 512:1024] = CTX[r]
__global__ __launch_bounds__(256) void concat_k(const float4* __restrict__ H2,
                                                const float4* __restrict__ CTX,
                                                float4* __restrict__ CC)
{
    int idx = blockIdx.x * 256 + threadIdx.x;    // over 1536*256 float4
    int r = idx >> 8;
    int c4 = idx & 255;
    float4 v = (c4 < 128) ? H2[r * 128 + c4] : CTX[r * 128 + (c4 - 128)];
    CC[idx] = v;
}

// ---------------------------------------------------------------------------
extern "C" void kernel_launch(void* const* d_in, const int* in_sizes, int n_in,
                              void* d_out, int out_size, void* d_ws, size_t ws_size,
                              hipStream_t stream)
{
    const int* input_b  = (const int*)d_in[0];
    const int* target_b = (const int*)d_in[1];
    const float* enc_emb = (const float*)d_in[2];
    const float* Wih_f = (const float*)d_in[3];
    const float* Whh_f = (const float*)d_in[4];
    const float* bih_f = (const float*)d_in[5];
    const float* bhh_f = (const float*)d_in[6];
    const float* Wih_b = (const float*)d_in[7];
    const float* Whh_b = (const float*)d_in[8];
    const float* bih_b = (const float*)d_in[9];
    const float* bhh_b = (const float*)d_in[10];
    const float* dec_emb = (const float*)d_in[11];
    const float* dWih = (const float*)d_in[12];
    const float* dWhh = (const float*)d_in[13];
    const float* dbih = (const float*)d_in[14];
    const float* dbhh = (const float*)d_in[15];
    const float* Wc = (const float*)d_in[16];
    const float* bc = (const float*)d_in[17];
    const float* Wo = (const float*)d_in[18];
    const float* bo = (const float*)d_in[19];
    float* out = (float*)d_out;

    // workspace layout (float units)
    float* ws  = (float*)d_ws;
    float* GIf = ws;                      // 2359296
    float* GIb = GIf + 2359296;           // 2359296
    float* GId = GIb + 2359296;           // 2359296
    float* Hf  = GId + 2359296;           // 786432
    float* Hb  = Hf + 786432;             // 786432
    float* H2  = Hb + 786432;             // 786432
    float* ES  = H2 + 786432;             // 786432
    float* CTX = ES + 786432;             // 786432
    float* Wsp = CTX + 786432;            // 2359296 floats = 6 bf16 arrays of 786432
    float* HspF = Wsp + 2359296;          // 65536 floats = 131072 bf16
    // bf16 views
    __bf16* Wfh = (__bf16*)Wsp;
    __bf16* Wfl = Wfh + 786432;
    __bf16* Wbh = Wfl + 786432;
    __bf16* Wbl = Wbh + 786432;
    __bf16* Wdh = Wbl + 786432;
    __bf16* Wdl = Wdh + 786432;
    __bf16* Hsp = (__bf16*)HspF;
    // aliases over dead-by-then regions:
    float* CC   = GIb;                    // [1536,1024] floats (Wc-GEMM input)
    __bf16* Chi = (__bf16*)GIf;           // [1536,512] bf16
    __bf16* Clo = Chi + 786432;           // [1536,512] bf16

    // ---- pre-split recurrent weights ----
    split_w<<<384, 256, 0, stream>>>(Whh_f, Wfh, Wfl, 98304);
    split_w<<<384, 256, 0, stream>>>(Whh_b, Wbh, Wbl, 98304);
    split_w<<<384, 256, 0, stream>>>(dWhh,  Wdh, Wdl, 98304);

    // ---- gi precompute (embedding gather fused), MFMA path ----
    gemm_mfma<1, 0, 0><<<dim3(12, 12), 256, 0, stream>>>(nullptr, enc_emb, input_b,
        Wih_f, bih_f, GIf, nullptr, nullptr, 1536, 1536, 512);
    gemm_mfma<1, 0, 0><<<dim3(12, 12), 256, 0, stream>>>(nullptr, enc_emb, input_b,
        Wih_b, bih_b, GIb, nullptr, nullptr, 1536, 1536, 512);
    gemm_mfma<2, 0, 0><<<dim3(12, 12), 256, 0, stream>>>(nullptr, dec_emb, target_b,
        dWih, dbih, GId, nullptr, nullptr, 1536, 1536, 512);

    // ---- persistent cooperative recurrence (enc fwd+bwd, ES, decoder) ----
    {
        const float *aGIf = GIf, *aGIb = GIb, *aGId = GId;
        const __bf16 *aWfh = Wfh, *aWfl = Wfl, *aWbh = Wbh, *aWbl = Wbl,
                     *aWdh = Wdh, *aWdl = Wdl;
        const float *abf = bhh_f, *abb = bhh_b, *abd = dbhh;
        float *aHf = Hf, *aHb = Hb, *aH2 = H2, *aES = ES;
        __bf16 *aHsp = Hsp;
        void* args[] = {&aGIf, &aGIb, &aGId, &aWfh, &aWfl, &aWbh, &aWbl,
                        &aWdh, &aWdl, &abf, &abb, &abd, &aHf, &aHb, &aH2,
                        &aHsp, &aES};
        hipLaunchCooperativeKernel((const void*)recurrence, dim3(64), dim3(128),
                                   args, 0, stream);
    }

    // ---- attention for all (t,b) ----
    attention<<<384, 256, 0, stream>>>(H2, ES, CTX);

    // ---- concat [h2, ctx]; c = tanh(CC @ Wc^T + bc) written pre-split ----
    concat_k<<<1536, 256, 0, stream>>>((const float4*)H2, (const float4*)CTX, (float4*)CC);
    gemm_mfma<0, 1, 1><<<dim3(12, 4), 256, 0, stream>>>(CC, nullptr, nullptr,
        Wc, bc, nullptr, Chi, Clo, 1536, 512, 1024);

    // ---- logits = c @ Wo^T + bo ----
    gemm_logits<<<dim3(6, 250), 256, 0, stream>>>(Chi, Clo, Wo, bo, out,
        1536, VOUT, 512);
}

// Round 4
// 1862.967 us; speedup vs baseline: 1.4146x; 1.4146x over previous
//
#include <hip/hip_runtime.h>
#include <math.h>

#define HD   512
#define H3   1536
#define SLEN 48
#define TLEN 48
#define BSZ  32
#define VOUT 32000

__device__ __forceinline__ float sigm(float x) { return 1.0f / (1.0f + __expf(-x)); }

typedef __attribute__((ext_vector_type(8))) __bf16 bf16x8;
typedef __attribute__((ext_vector_type(4))) float f32x4;

// barrier state: [cnt0, gen0, cnt1, gen1]  (group 0 = fwd+dec, group 1 = bwd)
__device__ unsigned g_bar[4];

__global__ void bar_init()
{
    if (threadIdx.x < 4)
        __hip_atomic_store(&g_bar[threadIdx.x], 0u, __ATOMIC_RELAXED,
                           __HIP_MEMORY_SCOPE_AGENT);
}

// ---------------------------------------------------------------------------
// split fp32 -> bf16 hi/lo arrays (8 elems/thread)
// ---------------------------------------------------------------------------
__global__ __launch_bounds__(256) void split_w(const float* __restrict__ src,
                                               __bf16* __restrict__ hi,
                                               __bf16* __restrict__ lo, int n8)
{
    int i = blockIdx.x * 256 + threadIdx.x;
    if (i >= n8) return;
    float4 a = ((const float4*)src)[i * 2];
    float4 b = ((const float4*)src)[i * 2 + 1];
    float v[8] = {a.x, a.y, a.z, a.w, b.x, b.y, b.z, b.w};
    bf16x8 h, l;
#pragma unroll
    for (int j = 0; j < 8; j++) {
        __bf16 hb = (__bf16)v[j];
        h[j] = hb;
        l[j] = (__bf16)(v[j] - (float)hb);
    }
    ((bf16x8*)hi)[i] = h;
    ((bf16x8*)lo)[i] = l;
}

// ---------------------------------------------------------------------------
// MFMA bf16x3-split NT GEMM, fp32 inputs (in-kernel split), optional gather
// and optional split-bf16 output. 128x128 block, 4 waves (2x2), 64x64/wave.
// ---------------------------------------------------------------------------
template <int GATHER, int ACT, int OSPLIT>
__global__ __launch_bounds__(256, 2) void gemm_mfma(
    const float* __restrict__ A, const float* __restrict__ emb,
    const int* __restrict__ tokens, const float* __restrict__ Bt,
    const float* __restrict__ bias, float* __restrict__ Cout,
    __bf16* __restrict__ Chi, __bf16* __restrict__ Clo,
    int M, int N, int K)
{
    const int lane = threadIdx.x & 63;
    const int wave = threadIdx.x >> 6;
    const int wm = wave & 1, wn = wave >> 1;
    const int m0 = blockIdx.x * 128 + wm * 64;
    const int n0 = blockIdx.y * 128 + wn * 64;
    const int rl = lane & 15;
    const int kg = lane >> 4;

    const float* arow[4];
    const float* wrow[4];
#pragma unroll
    for (int f = 0; f < 4; f++) {
        int row = m0 + f * 16 + rl;
        if (GATHER == 0) {
            arow[f] = A + (size_t)row * K + kg * 8;
        } else if (GATHER == 1) {
            arow[f] = emb + (size_t)tokens[row] * K + kg * 8;
        } else {
            int t = row >> 5, b = row & 31;
            int tok = (t == 0) ? 1 : tokens[(t - 1) * 32 + b];
            arow[f] = emb + (size_t)tok * K + kg * 8;
        }
        wrow[f] = Bt + (size_t)(n0 + f * 16 + rl) * K + kg * 8;
    }

    f32x4 acc[4][4] = {};

    for (int k0 = 0; k0 < K; k0 += 32) {
        bf16x8 ah[4], al[4], wh[4], wl[4];
#pragma unroll
        for (int f = 0; f < 4; f++) {
            float4 x0 = *(const float4*)(arow[f] + k0);
            float4 x1 = *(const float4*)(arow[f] + k0 + 4);
            float4 y0 = *(const float4*)(wrow[f] + k0);
            float4 y1 = *(const float4*)(wrow[f] + k0 + 4);
            float xs[8] = {x0.x, x0.y, x0.z, x0.w, x1.x, x1.y, x1.z, x1.w};
            float ys[8] = {y0.x, y0.y, y0.z, y0.w, y1.x, y1.y, y1.z, y1.w};
            bf16x8 xh, xl, yh, yl;
#pragma unroll
            for (int j = 0; j < 8; j++) {
                __bf16 hb = (__bf16)xs[j];
                xh[j] = hb;
                xl[j] = (__bf16)(xs[j] - (float)hb);
                __bf16 hc = (__bf16)ys[j];
                yh[j] = hc;
                yl[j] = (__bf16)(ys[j] - (float)hc);
            }
            ah[f] = xh; al[f] = xl; wh[f] = yh; wl[f] = yl;
        }
#pragma unroll
        for (int fm = 0; fm < 4; fm++)
#pragma unroll
            for (int fn = 0; fn < 4; fn++) {
                acc[fm][fn] = __builtin_amdgcn_mfma_f32_16x16x32_bf16(
                    ah[fm], wh[fn], acc[fm][fn], 0, 0, 0);
                acc[fm][fn] = __builtin_amdgcn_mfma_f32_16x16x32_bf16(
                    ah[fm], wl[fn], acc[fm][fn], 0, 0, 0);
                acc[fm][fn] = __builtin_amdgcn_mfma_f32_16x16x32_bf16(
                    al[fm], wh[fn], acc[fm][fn], 0, 0, 0);
            }
    }

#pragma unroll
    for (int fn = 0; fn < 4; fn++) {
        float bb = bias[n0 + fn * 16 + rl];
#pragma unroll
        for (int fm = 0; fm < 4; fm++) {
            int mrow = m0 + fm * 16 + kg * 4;
            int ncol = n0 + fn * 16 + rl;
#pragma unroll
            for (int r = 0; r < 4; r++) {
                float v = acc[fm][fn][r] + bb;
                if (ACT == 1) v = tanhf(v);
                if (OSPLIT) {
                    __bf16 hh = (__bf16)v;
                    Chi[(size_t)(mrow + r) * N + ncol] = hh;
                    Clo[(size_t)(mrow + r) * N + ncol] = (__bf16)(v - (float)hh);
                } else {
                    Cout[(size_t)(mrow + r) * N + ncol] = v;
                }
            }
        }
    }
}

// ---------------------------------------------------------------------------
// Logits GEMM: A pre-split bf16 hi/lo [M,K]; W fp32 [N,K] staged+split via LDS.
// ---------------------------------------------------------------------------
__global__ __launch_bounds__(256, 1) void gemm_logits(
    const __bf16* __restrict__ Ahi, const __bf16* __restrict__ Alo,
    const float* __restrict__ W, const float* __restrict__ bias,
    float* __restrict__ Cout, int M, int N, int K)
{
    __shared__ __align__(16) __bf16 WL[2][8][64][8];
    const int lane = threadIdx.x & 63;
    const int wave = threadIdx.x >> 6;
    const int m0 = blockIdx.x * 256 + wave * 64;
    const int n0 = blockIdx.y * 128;
    const int rl = lane & 15, kg = lane >> 4;

    const __bf16* ap[4];
    const __bf16* alp[4];
#pragma unroll
    for (int mt = 0; mt < 4; mt++) {
        ap[mt]  = Ahi + (size_t)(m0 + mt * 16 + rl) * K + kg * 8;
        alp[mt] = Alo + (size_t)(m0 + mt * 16 + rl) * K + kg * 8;
    }

    const int snt = threadIdx.x >> 5;
    const int sl0 = (threadIdx.x & 31) * 2;

    f32x4 acc[4][8] = {};

    for (int kt = 0; kt < K; kt += 32) {
#pragma unroll
        for (int q = 0; q < 2; q++) {
            int l = sl0 + q;
            const float* wr = W + (size_t)(n0 + snt * 16 + (l & 15)) * K + kt + (l >> 4) * 8;
            float4 x0 = *(const float4*)wr;
            float4 x1 = *(const float4*)(wr + 4);
            float v[8] = {x0.x, x0.y, x0.z, x0.w, x1.x, x1.y, x1.z, x1.w};
            bf16x8 h, lo_;
#pragma unroll
            for (int j = 0; j < 8; j++) {
                __bf16 hb = (__bf16)v[j];
                h[j] = hb;
                lo_[j] = (__bf16)(v[j] - (float)hb);
            }
            *(bf16x8*)&WL[0][snt][l][0] = h;
            *(bf16x8*)&WL[1][snt][l][0] = lo_;
        }
        __syncthreads();
        bf16x8 a_h[4], a_l[4];
#pragma unroll
        for (int mt = 0; mt < 4; mt++) {
            a_h[mt] = *(const bf16x8*)(ap[mt] + kt);
            a_l[mt] = *(const bf16x8*)(alp[mt] + kt);
        }
#pragma unroll
        for (int nt = 0; nt < 8; nt++) {
            bf16x8 wh = *(const bf16x8*)&WL[0][nt][lane][0];
            bf16x8 wl = *(const bf16x8*)&WL[1][nt][lane][0];
#pragma unroll
            for (int mt = 0; mt < 4; mt++) {
                acc[mt][nt] = __builtin_amdgcn_mfma_f32_16x16x32_bf16(
                    a_h[mt], wh, acc[mt][nt], 0, 0, 0);
                acc[mt][nt] = __builtin_amdgcn_mfma_f32_16x16x32_bf16(
                    a_h[mt], wl, acc[mt][nt], 0, 0, 0);
                acc[mt][nt] = __builtin_amdgcn_mfma_f32_16x16x32_bf16(
                    a_l[mt], wh, acc[mt][nt], 0, 0, 0);
            }
        }
        __syncthreads();
    }

#pragma unroll
    for (int nt = 0; nt < 8; nt++) {
        int col = n0 + nt * 16 + rl;
        float bb = bias[col];
#pragma unroll
        for (int mt = 0; mt < 4; mt++) {
            int row = m0 + mt * 16 + kg * 4;
#pragma unroll
            for (int r = 0; r < 4; r++)
                Cout[(size_t)(row + r) * N + col] = acc[mt][nt][r] + bb;
        }
    }
}

// ---------------------------------------------------------------------------
// Persistent recurrence, fence-free sync (see R3 notes). Fixed this round:
// consumer A-frag base stride per mt block is 2048 ULLs (8192 bf16), was 1024.
// ---------------------------------------------------------------------------
typedef __bf16 wlds_t[3][16][64][8];

__device__ __forceinline__ void load_w(wlds_t* Wlds, const __bf16* __restrict__ Whi,
                                       const __bf16* __restrict__ Wlo, int i0, int tid)
{
    for (int idx = tid; idx < 3 * 16 * 64; idx += 128) {
        int g = idx >> 10, rem = idx & 1023, kk = rem >> 6, l = rem & 63;
        size_t src = (size_t)(g * HD + i0 + (l & 15)) * HD + kk * 32 + (l >> 4) * 8;
        *(bf16x8*)&Wlds[0][g][kk][l][0] = *(const bf16x8*)&Whi[src];
        *(bf16x8*)&Wlds[1][g][kk][l][0] = *(const bf16x8*)&Wlo[src];
    }
    __syncthreads();
}

__device__ __forceinline__ void group_barrier(unsigned* cnt, unsigned* gen,
                                              unsigned nwg, unsigned target)
{
    asm volatile("s_waitcnt vmcnt(0)" ::: "memory");   // all this wave's stores done
    __syncthreads();
    if (threadIdx.x == 0) {
        unsigned prev = __hip_atomic_fetch_add(cnt, 1u, __ATOMIC_RELAXED,
                                               __HIP_MEMORY_SCOPE_AGENT);
        if (prev == nwg - 1) {
            __hip_atomic_store(cnt, 0u, __ATOMIC_RELAXED, __HIP_MEMORY_SCOPE_AGENT);
            asm volatile("s_waitcnt vmcnt(0)" ::: "memory");  // cnt reset lands first
            __hip_atomic_store(gen, target, __ATOMIC_RELAXED, __HIP_MEMORY_SCOPE_AGENT);
        } else {
            while (__hip_atomic_fetch_add(gen, 0u, __ATOMIC_RELAXED,
                                          __HIP_MEMORY_SCOPE_AGENT) < target)
                __builtin_amdgcn_s_sleep(1);
        }
    }
    __syncthreads();
}

// Hsp block layout (per dir,parity): hi[mt(2)][kk(16)][lane(64)][8] then lo same.
#define HSPB 32768           // elems per (dir,parity) block
#define HSP_LO 16384         // lo offset within block

__device__ __forceinline__ void gru_step_mfma(
    const wlds_t* Wlds, int wave, int lane, int i0, int tfirst,
    const float* __restrict__ GIt, const __bf16* __restrict__ Hsp_prev,
    const float* __restrict__ bhh, const float* __restrict__ hprev,
    float* __restrict__ hout, __bf16* __restrict__ Hsp_out)
{
    f32x4 acc[3] = {};
    if (!tfirst) {
        // coalesced A-frag loads from LLC: elem off = mt*8192 + kk*512 + lane*8
        // ULL off = mt*2048 + kk*128 + lane*2; lo at +4096 ULLs (16384 elems)
        const unsigned long long* ap = (const unsigned long long*)Hsp_prev
                                       + wave * 2048 + lane * 2;
        unsigned long long hb[32], lb[32];
#pragma unroll
        for (int kk = 0; kk < 16; kk++) {
            hb[2 * kk]     = __hip_atomic_load(ap + kk * 128,        __ATOMIC_RELAXED, __HIP_MEMORY_SCOPE_AGENT);
            hb[2 * kk + 1] = __hip_atomic_load(ap + kk * 128 + 1,    __ATOMIC_RELAXED, __HIP_MEMORY_SCOPE_AGENT);
            lb[2 * kk]     = __hip_atomic_load(ap + 4096 + kk * 128,     __ATOMIC_RELAXED, __HIP_MEMORY_SCOPE_AGENT);
            lb[2 * kk + 1] = __hip_atomic_load(ap + 4096 + kk * 128 + 1, __ATOMIC_RELAXED, __HIP_MEMORY_SCOPE_AGENT);
        }
#pragma unroll
        for (int kk = 0; kk < 16; kk++) {
            union { unsigned long long u[2]; bf16x8 v; } af, av;
            af.u[0] = hb[2 * kk]; af.u[1] = hb[2 * kk + 1];
            av.u[0] = lb[2 * kk]; av.u[1] = lb[2 * kk + 1];
#pragma unroll
            for (int g = 0; g < 3; g++) {
                bf16x8 Wh = *(const bf16x8*)&Wlds[0][g][kk][lane][0];
                bf16x8 Wl = *(const bf16x8*)&Wlds[1][g][kk][lane][0];
                acc[g] = __builtin_amdgcn_mfma_f32_16x16x32_bf16(af.v, Wh, acc[g], 0, 0, 0);
                acc[g] = __builtin_amdgcn_mfma_f32_16x16x32_bf16(af.v, Wl, acc[g], 0, 0, 0);
                acc[g] = __builtin_amdgcn_mfma_f32_16x16x32_bf16(av.v, Wh, acc[g], 0, 0, 0);
            }
        }
    }
    const int ig = i0 + (lane & 15);
    const int bb = wave * 16 + (lane >> 4) * 4;
    float b_r = bhh[ig], b_z = bhh[HD + ig], b_n = bhh[2 * HD + ig];
    const int kk_p = ig >> 5;                       // A-frag coords of column ig
    const int lhi  = ((ig >> 3) & 3) << 4;
    const int e_p  = ig & 7;
#pragma unroll
    for (int r = 0; r < 4; r++) {
        int b = bb + r;
        float gr = acc[0][r] + GIt[(size_t)b * H3 + ig] + b_r;
        float gz = acc[1][r] + GIt[(size_t)b * H3 + HD + ig] + b_z;
        float gn = GIt[(size_t)b * H3 + 2 * HD + ig];
        float ghn = acc[2][r] + b_n;
        float rg = sigm(gr), zg = sigm(gz);
        float ng = tanhf(gn + rg * ghn);
        float hpi = tfirst ? 0.f : hprev[(size_t)b * HD + ig];
        float h = (1.f - zg) * ng + zg * hpi;
        hout[(size_t)b * HD + ig] = h;
        __bf16 hh = (__bf16)h;
        __bf16 hl = (__bf16)(h - (float)hh);
        // scatter into A-fragment layout
        size_t off = (size_t)(b >> 4) * 8192 + kk_p * 512 + ((b & 15) | lhi) * 8 + e_p;
        __hip_atomic_store((unsigned short*)(Hsp_out + off),
                           __builtin_bit_cast(unsigned short, hh),
                           __ATOMIC_RELAXED, __HIP_MEMORY_SCOPE_AGENT);
        __hip_atomic_store((unsigned short*)(Hsp_out + HSP_LO + off),
                           __builtin_bit_cast(unsigned short, hl),
                           __ATOMIC_RELAXED, __HIP_MEMORY_SCOPE_AGENT);
    }
}

__global__ __launch_bounds__(128) void recurrence(
    const float* __restrict__ GIf, const float* __restrict__ GIb,
    const float* __restrict__ GId,
    const __bf16* __restrict__ Wfh, const __bf16* __restrict__ Wfl,
    const __bf16* __restrict__ Wbh, const __bf16* __restrict__ Wbl,
    const __bf16* __restrict__ Wdh, const __bf16* __restrict__ Wdl,
    const float* __restrict__ bhf, const float* __restrict__ bhb,
    const float* __restrict__ bhd,
    float* __restrict__ Hf, float* __restrict__ Hb, float* __restrict__ H2,
    __bf16* __restrict__ Hsp)
{
    __shared__ __align__(16) __bf16 Wlds[2][3][16][64][8];   // 96 KB
    const int w = blockIdx.x;
    const int dir = w >> 5;
    const int i0 = (w & 31) * 16;
    const int wave = threadIdx.x >> 6, lane = threadIdx.x & 63;
    const int tid = threadIdx.x;
    unsigned* cnt = &g_bar[dir * 2];
    unsigned* gen = &g_bar[dir * 2 + 1];

    load_w((wlds_t*)Wlds, dir ? Wbh : Wfh, dir ? Wbl : Wfl, i0, tid);

    unsigned step = 0;

    // ---- phase 1: encoder ----
    for (int t = 0; t < SLEN; t++) {
        if (dir == 0) {
            gru_step_mfma((const wlds_t*)Wlds, wave, lane, i0, t == 0,
                GIf + (size_t)t * BSZ * H3,
                Hsp + (size_t)(0 * 2 + ((t + 1) & 1)) * HSPB,
                bhf, t ? Hf + (size_t)(t - 1) * BSZ * HD : (const float*)0,
                Hf + (size_t)t * BSZ * HD,
                Hsp + (size_t)(0 * 2 + (t & 1)) * HSPB);
        } else {
            int tb = SLEN - 1 - t;
            gru_step_mfma((const wlds_t*)Wlds, wave, lane, i0, t == 0,
                GIb + (size_t)tb * BSZ * H3,
                Hsp + (size_t)(1 * 2 + ((t + 1) & 1)) * HSPB,
                bhb, t ? Hb + (size_t)(tb + 1) * BSZ * HD : (const float*)0,
                Hb + (size_t)tb * BSZ * HD,
                Hsp + (size_t)(1 * 2 + (t & 1)) * HSPB);
        }
        step++;
        group_barrier(cnt, gen, 32, step);
    }

    if (dir == 1) return;   // bwd group done

    // ---- phase 2: decoder on fwd group (reload weights) ----
    load_w((wlds_t*)Wlds, Wdh, Wdl, i0, tid);
    for (int t = 0; t < TLEN; t++) {
        gru_step_mfma((const wlds_t*)Wlds, wave, lane, i0, 0,
            GId + (size_t)t * BSZ * H3,
            Hsp + (size_t)(0 * 2 + ((t + 1) & 1)) * HSPB,
            bhd,
            t ? H2 + (size_t)(t - 1) * BSZ * HD
              : Hf + (size_t)(SLEN - 1) * BSZ * HD,
            H2 + (size_t)t * BSZ * HD,
            Hsp + (size_t)(0 * 2 + (t & 1)) * HSPB);
        step++;
        group_barrier(cnt, gen, 32, step);
    }
}

// ---------------------------------------------------------------------------
// Attention: one wave per (t,b). scores over s -> softmax -> ctx.
// ---------------------------------------------------------------------------
__global__ __launch_bounds__(256) void attention(
    const float* __restrict__ H2, const float* __restrict__ ES,
    float* __restrict__ CTX)
{
    const int wid = (blockIdx.x * 256 + threadIdx.x) >> 6;
    const int lane = threadIdx.x & 63;
    const int t = wid >> 5, b = wid & 31;

    const float4* q = (const float4*)(H2 + ((size_t)t * BSZ + b) * HD);
    float4 q1 = q[lane], q2 = q[lane + 64];

    float sc = -1e30f;
    for (int s = 0; s < SLEN; s++) {
        const float4* e = (const float4*)(ES + ((size_t)s * BSZ + b) * HD);
        float4 e1 = e[lane], e2 = e[lane + 64];
        float p = q1.x * e1.x + q1.y * e1.y + q1.z * e1.z + q1.w * e1.w +
                  q2.x * e2.x + q2.y * e2.y + q2.z * e2.z + q2.w * e2.w;
#pragma unroll
        for (int d = 32; d >= 1; d >>= 1) p += __shfl_xor(p, d, 64);
        if (lane == s) sc = p;
    }
    float mx = sc;
#pragma unroll
    for (int d = 32; d >= 1; d >>= 1) mx = fmaxf(mx, __shfl_xor(mx, d, 64));
    float ex = (lane < SLEN) ? __expf(sc - mx) : 0.f;
    float sum = ex;
#pragma unroll
    for (int d = 32; d >= 1; d >>= 1) sum += __shfl_xor(sum, d, 64);
    float a = ex / sum;

    float4 c1 = {0.f, 0.f, 0.f, 0.f}, c2 = {0.f, 0.f, 0.f, 0.f};
    for (int s = 0; s < SLEN; s++) {
        float as = __shfl(a, s, 64);
        const float4* e = (const float4*)(ES + ((size_t)s * BSZ + b) * HD);
        float4 e1 = e[lane], e2 = e[lane + 64];
        c1.x = fmaf(as, e1.x, c1.x); c1.y = fmaf(as, e1.y, c1.y);
        c1.z = fmaf(as, e1.z, c1.z); c1.w = fmaf(as, e1.w, c1.w);
        c2.x = fmaf(as, e2.x, c2.x); c2.y = fmaf(as, e2.y, c2.y);
        c2.z = fmaf(as, e2.z, c2.z); c2.w = fmaf(as, e2.w, c2.w);
    }
    float4* co = (float4*)(CTX + ((size_t)t * BSZ + b) * HD);
    co[lane] = c1;
    co[lane + 64] = c2;
}

// ES = Hf + Hb (float4 elementwise)
__global__ __launch_bounds__(256) void add4(const float4* __restrict__ a,
                                            const float4* __restrict__ b,
                                            float4* __restrict__ o)
{
    int i = blockIdx.x * 256 + threadIdx.x;
    float4 x = a[i], y = b[i];
    float4 r = {x.x + y.x, x.y + y.y, x.z + y.z, x.w + y.w};
    o[i] = r;
}

// CC[r, 0:512] = H2[r], CC[r, 512:1024] = CTX[r]
__global__ __launch_bounds__(256) void concat_k(const float4* __restrict__ H2,
                                                const float4* __restrict__ CTX,
                                                float4* __restrict__ CC)
{
    int idx = blockIdx.x * 256 + threadIdx.x;
    int r = idx >> 8;
    int c4 = idx & 255;
    float4 v = (c4 < 128) ? H2[r * 128 + c4] : CTX[r * 128 + (c4 - 128)];
    CC[idx] = v;
}

// ---------------------------------------------------------------------------
extern "C" void kernel_launch(void* const* d_in, const int* in_sizes, int n_in,
                              void* d_out, int out_size, void* d_ws, size_t ws_size,
                              hipStream_t stream)
{
    const int* input_b  = (const int*)d_in[0];
    const int* target_b = (const int*)d_in[1];
    const float* enc_emb = (const float*)d_in[2];
    const float* Wih_f = (const float*)d_in[3];
    const float* Whh_f = (const float*)d_in[4];
    const float* bih_f = (const float*)d_in[5];
    const float* bhh_f = (const float*)d_in[6];
    const float* Wih_b = (const float*)d_in[7];
    const float* Whh_b = (const float*)d_in[8];
    const float* bih_b = (const float*)d_in[9];
    const float* bhh_b = (const float*)d_in[10];
    const float* dec_emb = (const float*)d_in[11];
    const float* dWih = (const float*)d_in[12];
    const float* dWhh = (const float*)d_in[13];
    const float* dbih = (const float*)d_in[14];
    const float* dbhh = (const float*)d_in[15];
    const float* Wc = (const float*)d_in[16];
    const float* bc = (const float*)d_in[17];
    const float* Wo = (const float*)d_in[18];
    const float* bo = (const float*)d_in[19];
    float* out = (float*)d_out;

    // workspace layout (float units)
    float* ws  = (float*)d_ws;
    float* GIf = ws;                      // 2359296
    float* GIb = GIf + 2359296;           // 2359296
    float* GId = GIb + 2359296;           // 2359296
    float* Hf  = GId + 2359296;           // 786432
    float* Hb  = Hf + 786432;             // 786432
    float* H2  = Hb + 786432;             // 786432
    float* ES  = H2 + 786432;             // 786432
    float* CTX = ES + 786432;             // 786432
    float* Wsp = CTX + 786432;            // 2359296 floats = 6 bf16 arrays
    float* HspF = Wsp + 2359296;          // 65536 floats = 131072 bf16
    __bf16* Wfh = (__bf16*)Wsp;
    __bf16* Wfl = Wfh + 786432;
    __bf16* Wbh = Wfl + 786432;
    __bf16* Wbl = Wbh + 786432;
    __bf16* Wdh = Wbl + 786432;
    __bf16* Wdl = Wdh + 786432;
    __bf16* Hsp = (__bf16*)HspF;
    float* CC   = GIb;                    // alias (dead region by then)
    __bf16* Chi = (__bf16*)GIf;
    __bf16* Clo = Chi + 786432;

    // ---- barrier init + pre-split recurrent weights ----
    bar_init<<<1, 64, 0, stream>>>();
    split_w<<<384, 256, 0, stream>>>(Whh_f, Wfh, Wfl, 98304);
    split_w<<<384, 256, 0, stream>>>(Whh_b, Wbh, Wbl, 98304);
    split_w<<<384, 256, 0, stream>>>(dWhh,  Wdh, Wdl, 98304);

    // ---- gi precompute (embedding gather fused) ----
    gemm_mfma<1, 0, 0><<<dim3(12, 12), 256, 0, stream>>>(nullptr, enc_emb, input_b,
        Wih_f, bih_f, GIf, nullptr, nullptr, 1536, 1536, 512);
    gemm_mfma<1, 0, 0><<<dim3(12, 12), 256, 0, stream>>>(nullptr, enc_emb, input_b,
        Wih_b, bih_b, GIb, nullptr, nullptr, 1536, 1536, 512);
    gemm_mfma<2, 0, 0><<<dim3(12, 12), 256, 0, stream>>>(nullptr, dec_emb, target_b,
        dWih, dbih, GId, nullptr, nullptr, 1536, 1536, 512);

    // ---- persistent recurrence (fence-free barrier) ----
    {
        const float *aGIf = GIf, *aGIb = GIb, *aGId = GId;
        const __bf16 *aWfh = Wfh, *aWfl = Wfl, *aWbh = Wbh, *aWbl = Wbl,
                     *aWdh = Wdh, *aWdl = Wdl;
        const float *abf = bhh_f, *abb = bhh_b, *abd = dbhh;
        float *aHf = Hf, *aHb = Hb, *aH2 = H2;
        __bf16 *aHsp = Hsp;
        void* args[] = {&aGIf, &aGIb, &aGId, &aWfh, &aWfl, &aWbh, &aWbl,
                        &aWdh, &aWdl, &abf, &abb, &abd, &aHf, &aHb, &aH2,
                        &aHsp};
        hipLaunchCooperativeKernel((const void*)recurrence, dim3(64), dim3(128),
                                   args, 0, stream);
    }

    // ---- ES = Hf + Hb ----
    add4<<<768, 256, 0, stream>>>((const float4*)Hf, (const float4*)Hb, (float4*)ES);

    // ---- attention ----
    attention<<<384, 256, 0, stream>>>(H2, ES, CTX);

    // ---- concat; c = tanh(CC @ Wc^T + bc) written pre-split ----
    concat_k<<<1536, 256, 0, stream>>>((const float4*)H2, (const float4*)CTX, (float4*)CC);
    gemm_mfma<0, 1, 1><<<dim3(12, 4), 256, 0, stream>>>(CC, nullptr, nullptr,
        Wc, bc, nullptr, Chi, Clo, 1536, 512, 1024);

    // ---- logits ----
    gemm_logits<<<dim3(6, 250), 256, 0, stream>>>(Chi, Clo, Wo, bo, out,
        1536, VOUT, 512);
}

// Round 6
// 1754.156 us; speedup vs baseline: 1.5024x; 1.0620x over previous
//
#include <hip/hip_runtime.h>
#include <math.h>

#define HD   512
#define H3   1536
#define SLEN 48
#define TLEN 48
#define BSZ  32
#define VOUT 32000

__device__ __forceinline__ float sigm(float x) { return 1.0f / (1.0f + __expf(-x)); }

typedef __attribute__((ext_vector_type(8))) __bf16 bf16x8;
typedef __attribute__((ext_vector_type(4))) float f32x4;

// barrier state: [cnt0, gen0, cnt1, gen1]  (group 0 = fwd+dec, group 1 = bwd)
__device__ unsigned g_bar[4];

// ---------------------------------------------------------------------------
// Fused: split 3 fp32 weight matrices -> bf16 hi/lo (blockIdx.y selects), and
// block (0,0) zeroes the barrier state (replaces bar_init launch).
// ---------------------------------------------------------------------------
__global__ __launch_bounds__(256) void split_w3(
    const float* __restrict__ s0, __bf16* __restrict__ h0, __bf16* __restrict__ l0,
    const float* __restrict__ s1, __bf16* __restrict__ h1, __bf16* __restrict__ l1,
    const float* __restrict__ s2, __bf16* __restrict__ h2, __bf16* __restrict__ l2,
    int n8)
{
    if (blockIdx.x == 0 && blockIdx.y == 0 && threadIdx.x < 4)
        __hip_atomic_store(&g_bar[threadIdx.x], 0u, __ATOMIC_RELAXED,
                           __HIP_MEMORY_SCOPE_AGENT);
    const float* src = (blockIdx.y == 0) ? s0 : (blockIdx.y == 1) ? s1 : s2;
    __bf16* hi = (blockIdx.y == 0) ? h0 : (blockIdx.y == 1) ? h1 : h2;
    __bf16* lo = (blockIdx.y == 0) ? l0 : (blockIdx.y == 1) ? l1 : l2;

    int i = blockIdx.x * 256 + threadIdx.x;
    if (i >= n8) return;
    float4 a = ((const float4*)src)[i * 2];
    float4 b = ((const float4*)src)[i * 2 + 1];
    float v[8] = {a.x, a.y, a.z, a.w, b.x, b.y, b.z, b.w};
    bf16x8 h, l;
#pragma unroll
    for (int j = 0; j < 8; j++) {
        __bf16 hb = (__bf16)v[j];
        h[j] = hb;
        l[j] = (__bf16)(v[j] - (float)hb);
    }
    ((bf16x8*)hi)[i] = h;
    ((bf16x8*)lo)[i] = l;
}

// ---------------------------------------------------------------------------
// Fused gi GEMM: one launch, blockIdx.z in {0: enc-fwd, 1: enc-bwd, 2: dec}.
// C = emb[tokens] @ W^T + bias, M=N=1536, K=512. bf16x3-split MFMA,
// 128x128 block, 4 waves (2x2), 64x64/wave. Gather mode uniform per block.
// ---------------------------------------------------------------------------
__global__ __launch_bounds__(256, 2) void gemm_gi(
    const float* __restrict__ emb1, const int* __restrict__ tok1,
    const float* __restrict__ W0, const float* __restrict__ b0, float* __restrict__ C0,
    const float* __restrict__ W1, const float* __restrict__ b1, float* __restrict__ C1,
    const float* __restrict__ emb2, const int* __restrict__ tok2,
    const float* __restrict__ W2, const float* __restrict__ b2, float* __restrict__ C2)
{
    const int z = blockIdx.z;
    const float* emb = (z == 2) ? emb2 : emb1;
    const int* tokens = (z == 2) ? tok2 : tok1;
    const float* Bt = (z == 0) ? W0 : (z == 1) ? W1 : W2;
    const float* bias = (z == 0) ? b0 : (z == 1) ? b1 : b2;
    float* Cout = (z == 0) ? C0 : (z == 1) ? C1 : C2;
    const int N = 1536, K = 512;

    const int lane = threadIdx.x & 63;
    const int wave = threadIdx.x >> 6;
    const int wm = wave & 1, wn = wave >> 1;
    const int m0 = blockIdx.x * 128 + wm * 64;
    const int n0 = blockIdx.y * 128 + wn * 64;
    const int rl = lane & 15;
    const int kg = lane >> 4;

    const float* arow[4];
    const float* wrow[4];
#pragma unroll
    for (int f = 0; f < 4; f++) {
        int row = m0 + f * 16 + rl;
        int tok;
        if (z == 2) {
            int t = row >> 5, b = row & 31;
            tok = (t == 0) ? 1 : tokens[(t - 1) * 32 + b];
        } else {
            tok = tokens[row];
        }
        arow[f] = emb + (size_t)tok * K + kg * 8;
        wrow[f] = Bt + (size_t)(n0 + f * 16 + rl) * K + kg * 8;
    }

    f32x4 acc[4][4] = {};

    for (int k0 = 0; k0 < K; k0 += 32) {
        bf16x8 ah[4], al[4], wh[4], wl[4];
#pragma unroll
        for (int f = 0; f < 4; f++) {
            float4 x0 = *(const float4*)(arow[f] + k0);
            float4 x1 = *(const float4*)(arow[f] + k0 + 4);
            float4 y0 = *(const float4*)(wrow[f] + k0);
            float4 y1 = *(const float4*)(wrow[f] + k0 + 4);
            float xs[8] = {x0.x, x0.y, x0.z, x0.w, x1.x, x1.y, x1.z, x1.w};
            float ys[8] = {y0.x, y0.y, y0.z, y0.w, y1.x, y1.y, y1.z, y1.w};
            bf16x8 xh, xl, yh, yl;
#pragma unroll
            for (int j = 0; j < 8; j++) {
                __bf16 hb = (__bf16)xs[j];
                xh[j] = hb;
                xl[j] = (__bf16)(xs[j] - (float)hb);
                __bf16 hc = (__bf16)ys[j];
                yh[j] = hc;
                yl[j] = (__bf16)(ys[j] - (float)hc);
            }
            ah[f] = xh; al[f] = xl; wh[f] = yh; wl[f] = yl;
        }
#pragma unroll
        for (int fm = 0; fm < 4; fm++)
#pragma unroll
            for (int fn = 0; fn < 4; fn++) {
                acc[fm][fn] = __builtin_amdgcn_mfma_f32_16x16x32_bf16(
                    ah[fm], wh[fn], acc[fm][fn], 0, 0, 0);
                acc[fm][fn] = __builtin_amdgcn_mfma_f32_16x16x32_bf16(
                    ah[fm], wl[fn], acc[fm][fn], 0, 0, 0);
                acc[fm][fn] = __builtin_amdgcn_mfma_f32_16x16x32_bf16(
                    al[fm], wh[fn], acc[fm][fn], 0, 0, 0);
            }
    }

#pragma unroll
    for (int fn = 0; fn < 4; fn++) {
        float bb = bias[n0 + fn * 16 + rl];
#pragma unroll
        for (int fm = 0; fm < 4; fm++) {
            int mrow = m0 + fm * 16 + kg * 4;
            int ncol = n0 + fn * 16 + rl;
#pragma unroll
            for (int r = 0; r < 4; r++)
                Cout[(size_t)(mrow + r) * N + ncol] = acc[fm][fn][r] + bb;
        }
    }
}

// ---------------------------------------------------------------------------
// MFMA bf16x3-split NT GEMM (dense A), optional tanh + split-bf16 output.
// Used for the Wc GEMM. 128x128 block, 4 waves.
// ---------------------------------------------------------------------------
template <int ACT, int OSPLIT>
__global__ __launch_bounds__(256, 2) void gemm_mfma(
    const float* __restrict__ A, const float* __restrict__ Bt,
    const float* __restrict__ bias, float* __restrict__ Cout,
    __bf16* __restrict__ Chi, __bf16* __restrict__ Clo,
    int M, int N, int K)
{
    const int lane = threadIdx.x & 63;
    const int wave = threadIdx.x >> 6;
    const int wm = wave & 1, wn = wave >> 1;
    const int m0 = blockIdx.x * 128 + wm * 64;
    const int n0 = blockIdx.y * 128 + wn * 64;
    const int rl = lane & 15;
    const int kg = lane >> 4;

    const float* arow[4];
    const float* wrow[4];
#pragma unroll
    for (int f = 0; f < 4; f++) {
        arow[f] = A + (size_t)(m0 + f * 16 + rl) * K + kg * 8;
        wrow[f] = Bt + (size_t)(n0 + f * 16 + rl) * K + kg * 8;
    }

    f32x4 acc[4][4] = {};

    for (int k0 = 0; k0 < K; k0 += 32) {
        bf16x8 ah[4], al[4], wh[4], wl[4];
#pragma unroll
        for (int f = 0; f < 4; f++) {
            float4 x0 = *(const float4*)(arow[f] + k0);
            float4 x1 = *(const float4*)(arow[f] + k0 + 4);
            float4 y0 = *(const float4*)(wrow[f] + k0);
            float4 y1 = *(const float4*)(wrow[f] + k0 + 4);
            float xs[8] = {x0.x, x0.y, x0.z, x0.w, x1.x, x1.y, x1.z, x1.w};
            float ys[8] = {y0.x, y0.y, y0.z, y0.w, y1.x, y1.y, y1.z, y1.w};
            bf16x8 xh, xl, yh, yl;
#pragma unroll
            for (int j = 0; j < 8; j++) {
                __bf16 hb = (__bf16)xs[j];
                xh[j] = hb;
                xl[j] = (__bf16)(xs[j] - (float)hb);
                __bf16 hc = (__bf16)ys[j];
                yh[j] = hc;
                yl[j] = (__bf16)(ys[j] - (float)hc);
            }
            ah[f] = xh; al[f] = xl; wh[f] = yh; wl[f] = yl;
        }
#pragma unroll
        for (int fm = 0; fm < 4; fm++)
#pragma unroll
            for (int fn = 0; fn < 4; fn++) {
                acc[fm][fn] = __builtin_amdgcn_mfma_f32_16x16x32_bf16(
                    ah[fm], wh[fn], acc[fm][fn], 0, 0, 0);
                acc[fm][fn] = __builtin_amdgcn_mfma_f32_16x16x32_bf16(
                    ah[fm], wl[fn], acc[fm][fn], 0, 0, 0);
                acc[fm][fn] = __builtin_amdgcn_mfma_f32_16x16x32_bf16(
                    al[fm], wh[fn], acc[fm][fn], 0, 0, 0);
            }
    }

#pragma unroll
    for (int fn = 0; fn < 4; fn++) {
        float bb = bias[n0 + fn * 16 + rl];
#pragma unroll
        for (int fm = 0; fm < 4; fm++) {
            int mrow = m0 + fm * 16 + kg * 4;
            int ncol = n0 + fn * 16 + rl;
#pragma unroll
            for (int r = 0; r < 4; r++) {
                float v = acc[fm][fn][r] + bb;
                if (ACT == 1) v = tanhf(v);
                if (OSPLIT) {
                    __bf16 hh = (__bf16)v;
                    Chi[(size_t)(mrow + r) * N + ncol] = hh;
                    Clo[(size_t)(mrow + r) * N + ncol] = (__bf16)(v - (float)hh);
                } else {
                    Cout[(size_t)(mrow + r) * N + ncol] = v;
                }
            }
        }
    }
}

// ---------------------------------------------------------------------------
// Logits GEMM: A pre-split bf16 hi/lo [M,K]; W fp32 [N,K] staged+split via LDS.
// ---------------------------------------------------------------------------
__global__ __launch_bounds__(256, 1) void gemm_logits(
    const __bf16* __restrict__ Ahi, const __bf16* __restrict__ Alo,
    const float* __restrict__ W, const float* __restrict__ bias,
    float* __restrict__ Cout, int M, int N, int K)
{
    __shared__ __align__(16) __bf16 WL[2][8][64][8];
    const int lane = threadIdx.x & 63;
    const int wave = threadIdx.x >> 6;
    const int m0 = blockIdx.x * 256 + wave * 64;
    const int n0 = blockIdx.y * 128;
    const int rl = lane & 15, kg = lane >> 4;

    const __bf16* ap[4];
    const __bf16* alp[4];
#pragma unroll
    for (int mt = 0; mt < 4; mt++) {
        ap[mt]  = Ahi + (size_t)(m0 + mt * 16 + rl) * K + kg * 8;
        alp[mt] = Alo + (size_t)(m0 + mt * 16 + rl) * K + kg * 8;
    }

    const int snt = threadIdx.x >> 5;
    const int sl0 = (threadIdx.x & 31) * 2;

    f32x4 acc[4][8] = {};

    for (int kt = 0; kt < K; kt += 32) {
#pragma unroll
        for (int q = 0; q < 2; q++) {
            int l = sl0 + q;
            const float* wr = W + (size_t)(n0 + snt * 16 + (l & 15)) * K + kt + (l >> 4) * 8;
            float4 x0 = *(const float4*)wr;
            float4 x1 = *(const float4*)(wr + 4);
            float v[8] = {x0.x, x0.y, x0.z, x0.w, x1.x, x1.y, x1.z, x1.w};
            bf16x8 h, lo_;
#pragma unroll
            for (int j = 0; j < 8; j++) {
                __bf16 hb = (__bf16)v[j];
                h[j] = hb;
                lo_[j] = (__bf16)(v[j] - (float)hb);
            }
            *(bf16x8*)&WL[0][snt][l][0] = h;
            *(bf16x8*)&WL[1][snt][l][0] = lo_;
        }
        __syncthreads();
        bf16x8 a_h[4], a_l[4];
#pragma unroll
        for (int mt = 0; mt < 4; mt++) {
            a_h[mt] = *(const bf16x8*)(ap[mt] + kt);
            a_l[mt] = *(const bf16x8*)(alp[mt] + kt);
        }
#pragma unroll
        for (int nt = 0; nt < 8; nt++) {
            bf16x8 wh = *(const bf16x8*)&WL[0][nt][lane][0];
            bf16x8 wl = *(const bf16x8*)&WL[1][nt][lane][0];
#pragma unroll
            for (int mt = 0; mt < 4; mt++) {
                acc[mt][nt] = __builtin_amdgcn_mfma_f32_16x16x32_bf16(
                    a_h[mt], wh, acc[mt][nt], 0, 0, 0);
                acc[mt][nt] = __builtin_amdgcn_mfma_f32_16x16x32_bf16(
                    a_h[mt], wl, acc[mt][nt], 0, 0, 0);
                acc[mt][nt] = __builtin_amdgcn_mfma_f32_16x16x32_bf16(
                    a_l[mt], wh, acc[mt][nt], 0, 0, 0);
            }
        }
        __syncthreads();
    }

#pragma unroll
    for (int nt = 0; nt < 8; nt++) {
        int col = n0 + nt * 16 + rl;
        float bb = bias[col];
#pragma unroll
        for (int mt = 0; mt < 4; mt++) {
            int row = m0 + mt * 16 + kg * 4;
#pragma unroll
            for (int r = 0; r < 4; r++)
                Cout[(size_t)(row + r) * N + col] = acc[mt][nt][r] + bb;
        }
    }
}

// ---------------------------------------------------------------------------
// Persistent recurrence — EXACT R4-proven structure (RMW barrier). Only
// change: spin backoff s_sleep(1) -> s_sleep(16) to cut gen-line contention.
// ---------------------------------------------------------------------------
typedef __bf16 wlds_t[3][16][64][8];

__device__ __forceinline__ void load_w(wlds_t* Wlds, const __bf16* __restrict__ Whi,
                                       const __bf16* __restrict__ Wlo, int i0, int tid)
{
    for (int idx = tid; idx < 3 * 16 * 64; idx += 128) {
        int g = idx >> 10, rem = idx & 1023, kk = rem >> 6, l = rem & 63;
        size_t src = (size_t)(g * HD + i0 + (l & 15)) * HD + kk * 32 + (l >> 4) * 8;
        *(bf16x8*)&Wlds[0][g][kk][l][0] = *(const bf16x8*)&Whi[src];
        *(bf16x8*)&Wlds[1][g][kk][l][0] = *(const bf16x8*)&Wlo[src];
    }
    __syncthreads();
}

__device__ __forceinline__ void group_barrier(unsigned* cnt, unsigned* gen,
                                              unsigned nwg, unsigned target)
{
    asm volatile("s_waitcnt vmcnt(0)" ::: "memory");   // all this wave's mem ops done
    __syncthreads();
    if (threadIdx.x == 0) {
        unsigned prev = __hip_atomic_fetch_add(cnt, 1u, __ATOMIC_RELAXED,
                                               __HIP_MEMORY_SCOPE_AGENT);
        if (prev == nwg - 1) {
            __hip_atomic_store(cnt, 0u, __ATOMIC_RELAXED, __HIP_MEMORY_SCOPE_AGENT);
            asm volatile("s_waitcnt vmcnt(0)" ::: "memory");  // cnt reset lands first
            __hip_atomic_store(gen, target, __ATOMIC_RELAXED, __HIP_MEMORY_SCOPE_AGENT);
        } else {
            while (__hip_atomic_fetch_add(gen, 0u, __ATOMIC_RELAXED,
                                          __HIP_MEMORY_SCOPE_AGENT) < target)
                __builtin_amdgcn_s_sleep(16);
        }
    }
    __syncthreads();
}

// Hsp block layout (per dir,parity): hi[mt(2)][kk(16)][lane(64)][8] then lo same.
#define HSPB 32768           // elems per (dir,parity) block
#define HSP_LO 16384         // lo offset within block

__device__ __forceinline__ void gru_step_mfma(
    const wlds_t* Wlds, int wave, int lane, int i0, int tfirst,
    const float* __restrict__ GIt, const __bf16* __restrict__ Hsp_prev,
    const float* __restrict__ bhh, const float* __restrict__ hprev,
    float* __restrict__ hout, __bf16* __restrict__ Hsp_out)
{
    f32x4 acc[3] = {};
    if (!tfirst) {
        // coalesced A-frag loads from LLC: ULL off = mt*2048 + kk*128 + lane*2
        const unsigned long long* ap = (const unsigned long long*)Hsp_prev
                                       + wave * 2048 + lane * 2;
        unsigned long long hb[32], lb[32];
#pragma unroll
        for (int kk = 0; kk < 16; kk++) {
            hb[2 * kk]     = __hip_atomic_load(ap + kk * 128,        __ATOMIC_RELAXED, __HIP_MEMORY_SCOPE_AGENT);
            hb[2 * kk + 1] = __hip_atomic_load(ap + kk * 128 + 1,    __ATOMIC_RELAXED, __HIP_MEMORY_SCOPE_AGENT);
            lb[2 * kk]     = __hip_atomic_load(ap + 4096 + kk * 128,     __ATOMIC_RELAXED, __HIP_MEMORY_SCOPE_AGENT);
            lb[2 * kk + 1] = __hip_atomic_load(ap + 4096 + kk * 128 + 1, __ATOMIC_RELAXED, __HIP_MEMORY_SCOPE_AGENT);
        }
#pragma unroll
        for (int kk = 0; kk < 16; kk++) {
            union { unsigned long long u[2]; bf16x8 v; } af, av;
            af.u[0] = hb[2 * kk]; af.u[1] = hb[2 * kk + 1];
            av.u[0] = lb[2 * kk]; av.u[1] = lb[2 * kk + 1];
#pragma unroll
            for (int g = 0; g < 3; g++) {
                bf16x8 Wh = *(const bf16x8*)&Wlds[0][g][kk][lane][0];
                bf16x8 Wl = *(const bf16x8*)&Wlds[1][g][kk][lane][0];
                acc[g] = __builtin_amdgcn_mfma_f32_16x16x32_bf16(af.v, Wh, acc[g], 0, 0, 0);
                acc[g] = __builtin_amdgcn_mfma_f32_16x16x32_bf16(af.v, Wl, acc[g], 0, 0, 0);
                acc[g] = __builtin_amdgcn_mfma_f32_16x16x32_bf16(av.v, Wh, acc[g], 0, 0, 0);
            }
        }
    }
    const int ig = i0 + (lane & 15);
    const int bb = wave * 16 + (lane >> 4) * 4;
    float b_r = bhh[ig], b_z = bhh[HD + ig], b_n = bhh[2 * HD + ig];
    const int kk_p = ig >> 5;                       // A-frag coords of column ig
    const int lhi  = ((ig >> 3) & 3) << 4;
    const int e_p  = ig & 7;
#pragma unroll
    for (int r = 0; r < 4; r++) {
        int b = bb + r;
        float gr = acc[0][r] + GIt[(size_t)b * H3 + ig] + b_r;
        float gz = acc[1][r] + GIt[(size_t)b * H3 + HD + ig] + b_z;
        float gn = GIt[(size_t)b * H3 + 2 * HD + ig];
        float ghn = acc[2][r] + b_n;
        float rg = sigm(gr), zg = sigm(gz);
        float ng = tanhf(gn + rg * ghn);
        float hpi = tfirst ? 0.f : hprev[(size_t)b * HD + ig];
        float h = (1.f - zg) * ng + zg * hpi;
        hout[(size_t)b * HD + ig] = h;
        __bf16 hh = (__bf16)h;
        __bf16 hl = (__bf16)(h - (float)hh);
        size_t off = (size_t)(b >> 4) * 8192 + kk_p * 512 + ((b & 15) | lhi) * 8 + e_p;
        __hip_atomic_store((unsigned short*)(Hsp_out + off),
                           __builtin_bit_cast(unsigned short, hh),
                           __ATOMIC_RELAXED, __HIP_MEMORY_SCOPE_AGENT);
        __hip_atomic_store((unsigned short*)(Hsp_out + HSP_LO + off),
                           __builtin_bit_cast(unsigned short, hl),
                           __ATOMIC_RELAXED, __HIP_MEMORY_SCOPE_AGENT);
    }
}

__global__ __launch_bounds__(128) void recurrence(
    const float* __restrict__ GIf, const float* __restrict__ GIb,
    const float* __restrict__ GId,
    const __bf16* __restrict__ Wfh, const __bf16* __restrict__ Wfl,
    const __bf16* __restrict__ Wbh, const __bf16* __restrict__ Wbl,
    const __bf16* __restrict__ Wdh, const __bf16* __restrict__ Wdl,
    const float* __restrict__ bhf, const float* __restrict__ bhb,
    const float* __restrict__ bhd,
    float* __restrict__ Hf, float* __restrict__ Hb, float* __restrict__ H2,
    __bf16* __restrict__ Hsp)
{
    __shared__ __align__(16) __bf16 Wlds[2][3][16][64][8];   // 96 KB
    const int w = blockIdx.x;
    const int dir = w >> 5;
    const int i0 = (w & 31) * 16;
    const int wave = threadIdx.x >> 6, lane = threadIdx.x & 63;
    const int tid = threadIdx.x;
    unsigned* cnt = &g_bar[dir * 2];
    unsigned* gen = &g_bar[dir * 2 + 1];

    load_w((wlds_t*)Wlds, dir ? Wbh : Wfh, dir ? Wbl : Wfl, i0, tid);

    unsigned step = 0;

    // ---- phase 1: encoder ----
    for (int t = 0; t < SLEN; t++) {
        if (dir == 0) {
            gru_step_mfma((const wlds_t*)Wlds, wave, lane, i0, t == 0,
                GIf + (size_t)t * BSZ * H3,
                Hsp + (size_t)(0 * 2 + ((t + 1) & 1)) * HSPB,
                bhf, t ? Hf + (size_t)(t - 1) * BSZ * HD : (const float*)0,
                Hf + (size_t)t * BSZ * HD,
                Hsp + (size_t)(0 * 2 + (t & 1)) * HSPB);
        } else {
            int tb = SLEN - 1 - t;
            gru_step_mfma((const wlds_t*)Wlds, wave, lane, i0, t == 0,
                GIb + (size_t)tb * BSZ * H3,
                Hsp + (size_t)(1 * 2 + ((t + 1) & 1)) * HSPB,
                bhb, t ? Hb + (size_t)(tb + 1) * BSZ * HD : (const float*)0,
                Hb + (size_t)tb * BSZ * HD,
                Hsp + (size_t)(1 * 2 + (t & 1)) * HSPB);
        }
        step++;
        group_barrier(cnt, gen, 32, step);
    }

    if (dir == 1) return;   // bwd group done

    // ---- phase 2: decoder on fwd group (reload weights) ----
    load_w((wlds_t*)Wlds, Wdh, Wdl, i0, tid);
    for (int t = 0; t < TLEN; t++) {
        gru_step_mfma((const wlds_t*)Wlds, wave, lane, i0, 0,
            GId + (size_t)t * BSZ * H3,
            Hsp + (size_t)(0 * 2 + ((t + 1) & 1)) * HSPB,
            bhd,
            t ? H2 + (size_t)(t - 1) * BSZ * HD
              : Hf + (size_t)(SLEN - 1) * BSZ * HD,
            H2 + (size_t)t * BSZ * HD,
            Hsp + (size_t)(0 * 2 + (t & 1)) * HSPB);
        step++;
        group_barrier(cnt, gen, 32, step);
    }
}

// ---------------------------------------------------------------------------
// Attention: one wave per (t,b). scores over s -> softmax -> ctx.
// ---------------------------------------------------------------------------
__global__ __launch_bounds__(256) void attention(
    const float* __restrict__ H2, const float* __restrict__ ES,
    float* __restrict__ CTX)
{
    const int wid = (blockIdx.x * 256 + threadIdx.x) >> 6;
    const int lane = threadIdx.x & 63;
    const int t = wid >> 5, b = wid & 31;

    const float4* q = (const float4*)(H2 + ((size_t)t * BSZ + b) * HD);
    float4 q1 = q[lane], q2 = q[lane + 64];

    float sc = -1e30f;
    for (int s = 0; s < SLEN; s++) {
        const float4* e = (const float4*)(ES + ((size_t)s * BSZ + b) * HD);
        float4 e1 = e[lane], e2 = e[lane + 64];
        float p = q1.x * e1.x + q1.y * e1.y + q1.z * e1.z + q1.w * e1.w +
                  q2.x * e2.x + q2.y * e2.y + q2.z * e2.z + q2.w * e2.w;
#pragma unroll
        for (int d = 32; d >= 1; d >>= 1) p += __shfl_xor(p, d, 64);
        if (lane == s) sc = p;
    }
    float mx = sc;
#pragma unroll
    for (int d = 32; d >= 1; d >>= 1) mx = fmaxf(mx, __shfl_xor(mx, d, 64));
    float ex = (lane < SLEN) ? __expf(sc - mx) : 0.f;
    float sum = ex;
#pragma unroll
    for (int d = 32; d >= 1; d >>= 1) sum += __shfl_xor(sum, d, 64);
    float a = ex / sum;

    float4 c1 = {0.f, 0.f, 0.f, 0.f}, c2 = {0.f, 0.f, 0.f, 0.f};
    for (int s = 0; s < SLEN; s++) {
        float as = __shfl(a, s, 64);
        const float4* e = (const float4*)(ES + ((size_t)s * BSZ + b) * HD);
        float4 e1 = e[lane], e2 = e[lane + 64];
        c1.x = fmaf(as, e1.x, c1.x); c1.y = fmaf(as, e1.y, c1.y);
        c1.z = fmaf(as, e1.z, c1.z); c1.w = fmaf(as, e1.w, c1.w);
        c2.x = fmaf(as, e2.x, c2.x); c2.y = fmaf(as, e2.y, c2.y);
        c2.z = fmaf(as, e2.z, c2.z); c2.w = fmaf(as, e2.w, c2.w);
    }
    float4* co = (float4*)(CTX + ((size_t)t * BSZ + b) * HD);
    co[lane] = c1;
    co[lane + 64] = c2;
}

// ES = Hf + Hb (float4 elementwise)
__global__ __launch_bounds__(256) void add4(const float4* __restrict__ a,
                                            const float4* __restrict__ b,
                                            float4* __restrict__ o)
{
    int i = blockIdx.x * 256 + threadIdx.x;
    float4 x = a[i], y = b[i];
    float4 r = {x.x + y.x, x.y + y.y, x.z + y.z, x.w + y.w};
    o[i] = r;
}

// CC[r, 0:512] = H2[r], CC[r, 512:1024] = CTX[r]
__global__ __launch_bounds__(256) void concat_k(const float4* __restrict__ H2,
                                                const float4* __restrict__ CTX,
                                                float4* __restrict__ CC)
{
    int idx = blockIdx.x * 256 + threadIdx.x;
    int r = idx >> 8;
    int c4 = idx & 255;
    float4 v = (c4 < 128) ? H2[r * 128 + c4] : CTX[r * 128 + (c4 - 128)];
    CC[idx] = v;
}

// ---------------------------------------------------------------------------
extern "C" void kernel_launch(void* const* d_in, const int* in_sizes, int n_in,
                              void* d_out, int out_size, void* d_ws, size_t ws_size,
                              hipStream_t stream)
{
    const int* input_b  = (const int*)d_in[0];
    const int* target_b = (const int*)d_in[1];
    const float* enc_emb = (const float*)d_in[2];
    const float* Wih_f = (const float*)d_in[3];
    const float* Whh_f = (const float*)d_in[4];
    const float* bih_f = (const float*)d_in[5];
    const float* bhh_f = (const float*)d_in[6];
    const float* Wih_b = (const float*)d_in[7];
    const float* Whh_b = (const float*)d_in[8];
    const float* bih_b = (const float*)d_in[9];
    const float* bhh_b = (const float*)d_in[10];
    const float* dec_emb = (const float*)d_in[11];
    const float* dWih = (const float*)d_in[12];
    const float* dWhh = (const float*)d_in[13];
    const float* dbih = (const float*)d_in[14];
    const float* dbhh = (const float*)d_in[15];
    const float* Wc = (const float*)d_in[16];
    const float* bc = (const float*)d_in[17];
    const float* Wo = (const float*)d_in[18];
    const float* bo = (const float*)d_in[19];
    float* out = (float*)d_out;

    // workspace layout (float units)
    float* ws  = (float*)d_ws;
    float* GIf = ws;                      // 2359296
    float* GIb = GIf + 2359296;           // 2359296
    float* GId = GIb + 2359296;           // 2359296
    float* Hf  = GId + 2359296;           // 786432
    float* Hb  = Hf + 786432;             // 786432
    float* H2  = Hb + 786432;             // 786432
    float* ES  = H2 + 786432;             // 786432
    float* CTX = ES + 786432;             // 786432
    float* Wsp = CTX + 786432;            // 2359296 floats = 6 bf16 arrays
    float* HspF = Wsp + 2359296;          // 65536 floats = 131072 bf16
    __bf16* Wfh = (__bf16*)Wsp;
    __bf16* Wfl = Wfh + 786432;
    __bf16* Wbh = Wfl + 786432;
    __bf16* Wbl = Wbh + 786432;
    __bf16* Wdh = Wbl + 786432;
    __bf16* Wdl = Wdh + 786432;
    __bf16* Hsp = (__bf16*)HspF;
    float* CC   = GIb;                    // alias (dead region by then)
    __bf16* Chi = (__bf16*)GIf;
    __bf16* Clo = Chi + 786432;

    // ---- barrier zero + pre-split recurrent weights (one fused launch) ----
    split_w3<<<dim3(384, 3), 256, 0, stream>>>(
        Whh_f, Wfh, Wfl, Whh_b, Wbh, Wbl, dWhh, Wdh, Wdl, 98304);

    // ---- gi precompute: all three in one launch (z selects) ----
    gemm_gi<<<dim3(12, 12, 3), 256, 0, stream>>>(
        enc_emb, input_b, Wih_f, bih_f, GIf,
        Wih_b, bih_b, GIb,
        dec_emb, target_b, dWih, dbih, GId);

    // ---- persistent recurrence (R4-proven barrier, bigger backoff) ----
    {
        const float *aGIf = GIf, *aGIb = GIb, *aGId = GId;
        const __bf16 *aWfh = Wfh, *aWfl = Wfl, *aWbh = Wbh, *aWbl = Wbl,
                     *aWdh = Wdh, *aWdl = Wdl;
        const float *abf = bhh_f, *abb = bhh_b, *abd = dbhh;
        float *aHf = Hf, *aHb = Hb, *aH2 = H2;
        __bf16 *aHsp = Hsp;
        void* args[] = {&aGIf, &aGIb, &aGId, &aWfh, &aWfl, &aWbh, &aWbl,
                        &aWdh, &aWdl, &abf, &abb, &abd, &aHf, &aHb, &aH2,
                        &aHsp};
        hipLaunchCooperativeKernel((const void*)recurrence, dim3(64), dim3(128),
                                   args, 0, stream);
    }

    // ---- ES = Hf + Hb ----
    add4<<<768, 256, 0, stream>>>((const float4*)Hf, (const float4*)Hb, (float4*)ES);

    // ---- attention ----
    attention<<<384, 256, 0, stream>>>(H2, ES, CTX);

    // ---- concat; c = tanh(CC @ Wc^T + bc) written pre-split ----
    concat_k<<<1536, 256, 0, stream>>>((const float4*)H2, (const float4*)CTX, (float4*)CC);
    gemm_mfma<1, 1><<<dim3(12, 4), 256, 0, stream>>>(CC, Wc, bc, nullptr,
        Chi, Clo, 1536, 512, 1024);

    // ---- logits ----
    gemm_logits<<<dim3(6, 250), 256, 0, stream>>>(Chi, Clo, Wo, bo, out,
        1536, VOUT, 512);
}